// Round 1
// baseline (12898.055 us; speedup 1.0000x reference)
//
#include <hip/hip_runtime.h>

// ---------------------------------------------------------------------------
// ADRNN: 2x (2-layer LSTM, H=512) pipeline, B=128, T=512.
// Architecture: 517 "tick" kernels (kernel boundary = global sync), stages
// software-pipelined across ticks:
//   tick k: r0(t=k) | r1(k-1) | rout(k-2) | t0(k-3) | t1(k-4) | tout(k-5)
// All cross-stage tensors (h, r_out16) are parity double-buffered (producer
// writes par=k&1, consumers read par^1; every edge is exactly 1 tick).
// Compute: fp16 MFMA 16x16x32, fp32 accumulate. Weights pre-converted to
// fp16 [n][k] (native B-fragment layout). c-state fp32, lane-owned.
// ---------------------------------------------------------------------------

typedef _Float16 half_t;
typedef _Float16 half8 __attribute__((ext_vector_type(8)));
typedef float floatx4 __attribute__((ext_vector_type(4)));

#define B_ 128
#define T_ 512
#define H_ 512

// half-unit offsets inside d_ws (region 1: halves)
#define OFF_W0 0        // r_Wih0 padded  [2048][64]
#define OFF_W1 131072   // r_Whh0         [2048][512]
#define OFF_W2 1179648  // r_Wih1         [2048][512]
#define OFF_W3 2228224  // r_Whh1         [2048][512]
#define OFF_W4 3276800  // t_Wih0 cols0-48 padded [2048][64]
#define OFF_W5 3407872  // t_Wih0 cols49-95 padded [2048][64]
#define OFF_W6 3538944  // t_Whh0         [2048][512]
#define OFF_W7 4587520  // t_Wih1         [2048][512]
#define OFF_W8 5636096  // t_Whh1         [2048][512]
#define OFF_W9 6684672  // Wr padded      [48][512]
#define OFF_W10 6709248 // Wt padded      [16][512]
#define W_TOTAL 6717440
#define H_BASE  6717440              // h[4 cells][2 par][128][512] halves
#define RO_BASE 7241728              // rout16[2 par][128][64] halves
#define HALF_TOTAL 7258112
// byte offsets
#define STATE_BYTE_OFF (H_BASE * 2)              // 13434880
#define STATE_BYTES (((HALF_TOTAL - H_BASE) * 2) + (4 * 65536 * 4)) // h+ro+c = 2129920
#define C_BYTE_OFF (HALF_TOTAL * 2)              // 14516224 (c: 4 cells x [128][512] f32)

#define TOUT_BASE (128 * 512 * 47)

__device__ __forceinline__ floatx4 mfma16(half8 a, half8 b, floatx4 c) {
  return __builtin_amdgcn_mfma_f32_16x16x32_f16(a, b, c, 0, 0, 0);
}

__device__ __forceinline__ float fast_sig(float x) {
  x = fminf(fmaxf(x, -30.f), 30.f);
  float e = __expf(-x);
  return __builtin_amdgcn_rcpf(1.f + e);
}
__device__ __forceinline__ float fast_tanh(float x) {
  x = fminf(fmaxf(x, -15.f), 15.f);
  float e = __expf(-2.f * x);
  return (1.f - e) * __builtin_amdgcn_rcpf(1.f + e);
}

// GEMM over one K-segment; A: fp16 [rows][lda], W: fp16 [2048 or NT*16][ldw].
// Wave computes MT m-tiles x NT n-tiles. Fragment layouts (gfx950 16x16x32):
//  A[m][k]: lane l holds m=l&15, k=(l>>4)*8+j  -> 16B contiguous load
//  B[k][n]: lane l holds n=l&15, k=(l>>4)*8+j  -> W[n][k] row-major 16B load
template <int MT, int NT, int K>
__device__ __forceinline__ void gemm_h(const half_t* __restrict__ A, int lda,
                                       const half_t* __restrict__ W, int ldw,
                                       const int* wrow, int m0, int lane,
                                       floatx4 (&acc)[MT][NT]) {
  const int lk = (lane >> 4) * 8;
  const int l15 = lane & 15;
#pragma unroll 2
  for (int ks = 0; ks < K / 32; ++ks) {
    const int kb = ks * 32 + lk;
    half8 a[MT], b[NT];
#pragma unroll
    for (int mt = 0; mt < MT; ++mt)
      a[mt] = *(const half8*)(A + (long)(m0 + mt * 16 + l15) * lda + kb);
#pragma unroll
    for (int nt = 0; nt < NT; ++nt)
      b[nt] = *(const half8*)(W + (long)(wrow[nt] + l15) * ldw + kb);
#pragma unroll
    for (int mt = 0; mt < MT; ++mt)
#pragma unroll
      for (int nt = 0; nt < NT; ++nt)
        acc[mt][nt] = mfma16(a[mt], b[nt], acc[mt][nt]);
  }
}

// K=64 segment whose A comes from fp32 x_r/x_t inline (k<47: x_r, 47..48: x_t, else 0)
template <int MT>
__device__ __forceinline__ void gemm_x(const float* __restrict__ xr,
                                       const float* __restrict__ xt, int t,
                                       const half_t* __restrict__ W,
                                       const int* wrow, int m0, int lane,
                                       floatx4 (&acc)[MT][4]) {
  const int lk = (lane >> 4) * 8;
  const int l15 = lane & 15;
#pragma unroll
  for (int ks = 0; ks < 2; ++ks) {
    const int kb = ks * 32 + lk;
    half8 b[4];
#pragma unroll
    for (int nt = 0; nt < 4; ++nt)
      b[nt] = *(const half8*)(W + (long)(wrow[nt] + l15) * 64 + kb);
    half8 a[MT];
#pragma unroll
    for (int mt = 0; mt < MT; ++mt) {
      const int row = m0 + mt * 16 + l15;
      const long base = (long)row * 512 + t;
#pragma unroll
      for (int j = 0; j < 8; ++j) {
        const int k = kb + j;
        float f = 0.f;
        if (k < 47) f = xr[base * 47 + k];
        else if (k < 49) f = xt[base * 2 + (k - 47)];
        a[mt][j] = (half_t)f;
      }
    }
#pragma unroll
    for (int mt = 0; mt < MT; ++mt)
#pragma unroll
      for (int nt = 0; nt < 4; ++nt)
        acc[mt][nt] = mfma16(a[mt], b[nt], acc[mt][nt]);
  }
}

// LSTM elementwise epilogue: acc tiles are [MT][4 gates(i,f,g,o)] at h-cols c0+(lane&15)
template <int MT>
__device__ __forceinline__ void lstm_epi(floatx4 (&acc)[MT][4],
                                         const float* __restrict__ bias,
                                         float* __restrict__ cst,
                                         half_t* __restrict__ hdst, int m0,
                                         int c0, int lane) {
  const int col = c0 + (lane & 15);
  const float bI = bias[col], bF = bias[512 + col], bG = bias[1024 + col],
              bO = bias[1536 + col];
#pragma unroll
  for (int mt = 0; mt < MT; ++mt)
#pragma unroll
    for (int r = 0; r < 4; ++r) {
      const int row = m0 + mt * 16 + ((lane >> 4) << 2) + r;
      const float gi = acc[mt][0][r] + bI;
      const float gf = acc[mt][1][r] + bF;
      const float gg = acc[mt][2][r] + bG;
      const float go = acc[mt][3][r] + bO;
      const int off = row * 512 + col;
      const float cold = cst[off];
      const float cn = fast_sig(gf) * cold + fast_sig(gi) * fast_tanh(gg);
      cst[off] = cn;
      hdst[off] = (half_t)(fast_sig(go) * fast_tanh(cn));
    }
}

__global__ __launch_bounds__(256) void tick_kernel(
    const float* __restrict__ xr, const float* __restrict__ xt,
    const float* __restrict__ b_r0, const float* __restrict__ b_r1,
    const float* __restrict__ b_t0, const float* __restrict__ b_t1,
    const float* __restrict__ brv, const float* __restrict__ btv,
    half_t* __restrict__ w16, float* __restrict__ cbase,
    float* __restrict__ out, int k) {
  const int bid = blockIdx.x;
  const int tid = threadIdx.x;
  const int lane = tid & 63;
  const int w = tid >> 6;
  const int par = k & 1, pq = par ^ 1;
  half_t* H = w16 + H_BASE;
  half_t* RO = w16 + RO_BASE;
#define HBUF(cell, p) (H + (((cell)*2 + (p)) << 16))

  if (bid < 128) {
    const int stage = bid >> 5;
    const int cs = bid & 31;
    const int c0 = cs * 16;
    const int sd[4] = {0, 1, 3, 4};
    const int t = k - sd[stage];
    if (t < 0 || t > 511) return;
    int wrow[4] = {c0, 512 + c0, 1024 + c0, 1536 + c0};
    floatx4 acc[2][4] = {};
    const int m0 = w * 32;
    if (stage == 0) {  // r0: gates = X(t)@r_Wih0^T + hr0(t-1)@r_Whh0^T
      gemm_x<2>(xr, xt, t, w16 + OFF_W0, wrow, m0, lane, acc);
      gemm_h<2, 4, 512>(HBUF(0, pq), 512, w16 + OFF_W1, 512, wrow, m0, lane, acc);
      lstm_epi<2>(acc, b_r0, cbase + 0 * 65536, HBUF(0, par), m0, c0, lane);
    } else if (stage == 1) {  // r1
      gemm_h<2, 4, 512>(HBUF(0, pq), 512, w16 + OFF_W2, 512, wrow, m0, lane, acc);
      gemm_h<2, 4, 512>(HBUF(1, pq), 512, w16 + OFF_W3, 512, wrow, m0, lane, acc);
      lstm_epi<2>(acc, b_r1, cbase + 1 * 65536, HBUF(1, par), m0, c0, lane);
    } else if (stage == 2) {  // t0: X + r_out16 + ht0 recurrent
      gemm_x<2>(xr, xt, t, w16 + OFF_W4, wrow, m0, lane, acc);
      gemm_h<2, 4, 64>(RO + pq * 8192, 64, w16 + OFF_W5, 64, wrow, m0, lane, acc);
      gemm_h<2, 4, 512>(HBUF(2, pq), 512, w16 + OFF_W6, 512, wrow, m0, lane, acc);
      lstm_epi<2>(acc, b_t0, cbase + 2 * 65536, HBUF(2, par), m0, c0, lane);
    } else {  // t1
      gemm_h<2, 4, 512>(HBUF(2, pq), 512, w16 + OFF_W7, 512, wrow, m0, lane, acc);
      gemm_h<2, 4, 512>(HBUF(3, pq), 512, w16 + OFF_W8, 512, wrow, m0, lane, acc);
      lstm_epi<2>(acc, b_t1, cbase + 3 * 65536, HBUF(3, par), m0, c0, lane);
    }
  } else if (bid < 130) {  // rout: r_out(t) = hr1(t)@Wr^T + br  -> d_out + fp16 copy
    const int t = k - 2;
    if (t < 0 || t > 511) return;
    const int rb = bid - 128;
    int wrow[3] = {0, 16, 32};
    floatx4 acc[1][3] = {};
    const int m0 = rb * 64 + w * 16;
    gemm_h<1, 3, 512>(HBUF(1, pq), 512, w16 + OFF_W9, 512, wrow, m0, lane, acc);
#pragma unroll
    for (int nt = 0; nt < 3; ++nt) {
      const int col = nt * 16 + (lane & 15);
#pragma unroll
      for (int r = 0; r < 4; ++r) {
        const int row = m0 + ((lane >> 4) << 2) + r;
        if (col < 47) {
          const float v = acc[0][nt][r] + brv[col];
          out[((long)row * 512 + t) * 47 + col] = v;
          RO[par * 8192 + row * 64 + col] = (half_t)v;
        } else if (col == 47) {
          RO[par * 8192 + row * 64 + col] = (half_t)0.f;
        }
      }
    }
  } else {  // tout: t_out(t) = ht1(t)@Wt^T + bt
    const int t = k - 5;
    if (t < 0 || t > 511) return;
    int wrow[1] = {0};
    floatx4 acc[2][1] = {};
    const int m0 = w * 32;
    gemm_h<2, 1, 512>(HBUF(3, pq), 512, w16 + OFF_W10, 512, wrow, m0, lane, acc);
    const int col = lane & 15;
    if (col < 2) {
#pragma unroll
      for (int mt = 0; mt < 2; ++mt)
#pragma unroll
        for (int r = 0; r < 4; ++r) {
          const int row = m0 + mt * 16 + ((lane >> 4) << 2) + r;
          out[TOUT_BASE + ((long)row * 512 + t) * 2 + col] = acc[mt][0][r] + btv[col];
        }
    }
  }
#undef HBUF
}

// fp32 -> fp16 weight conversion into [n][k] layout with zero padding.
__global__ __launch_bounds__(256) void conv_w(
    const float* __restrict__ rWih0, const float* __restrict__ rWhh0,
    const float* __restrict__ rWih1, const float* __restrict__ rWhh1,
    const float* __restrict__ tWih0, const float* __restrict__ tWhh0,
    const float* __restrict__ tWih1, const float* __restrict__ tWhh1,
    const float* __restrict__ Wr, const float* __restrict__ Wt,
    half_t* __restrict__ w16) {
  const int idx = blockIdx.x * 256 + threadIdx.x;
  if (idx >= W_TOTAL) return;
  float v = 0.f;
  if (idx < OFF_W1) {
    int n = idx >> 6, kk = idx & 63;
    if (kk < 49) v = rWih0[n * 49 + kk];
  } else if (idx < OFF_W2) {
    int r = idx - OFF_W1; v = rWhh0[((r >> 9) << 9) + (r & 511)];
  } else if (idx < OFF_W3) {
    int r = idx - OFF_W2; v = rWih1[r];
  } else if (idx < OFF_W4) {
    int r = idx - OFF_W3; v = rWhh1[r];
  } else if (idx < OFF_W5) {
    int r = idx - OFF_W4; int n = r >> 6, kk = r & 63;
    if (kk < 49) v = tWih0[n * 96 + kk];
  } else if (idx < OFF_W6) {
    int r = idx - OFF_W5; int n = r >> 6, kk = r & 63;
    if (kk < 47) v = tWih0[n * 96 + 49 + kk];
  } else if (idx < OFF_W7) {
    int r = idx - OFF_W6; v = tWhh0[r];
  } else if (idx < OFF_W8) {
    int r = idx - OFF_W7; v = tWih1[r];
  } else if (idx < OFF_W9) {
    int r = idx - OFF_W8; v = tWhh1[r];
  } else if (idx < OFF_W10) {
    int r = idx - OFF_W9; int n = r >> 9, kk = r & 511;
    if (n < 47) v = Wr[n * 512 + kk];
  } else {
    int r = idx - OFF_W10; int n = r >> 9, kk = r & 511;
    if (n < 2) v = Wt[n * 512 + kk];
  }
  w16[idx] = (half_t)v;
}

extern "C" void kernel_launch(void* const* d_in, const int* in_sizes, int n_in,
                              void* d_out, int out_size, void* d_ws,
                              size_t ws_size, hipStream_t stream) {
  const float* xr = (const float*)d_in[0];
  const float* xt = (const float*)d_in[1];
  const float* rWih0 = (const float*)d_in[2];
  const float* rWhh0 = (const float*)d_in[3];
  const float* r_b0 = (const float*)d_in[4];
  const float* rWih1 = (const float*)d_in[5];
  const float* rWhh1 = (const float*)d_in[6];
  const float* r_b1 = (const float*)d_in[7];
  const float* tWih0 = (const float*)d_in[8];
  const float* tWhh0 = (const float*)d_in[9];
  const float* t_b0 = (const float*)d_in[10];
  const float* tWih1 = (const float*)d_in[11];
  const float* tWhh1 = (const float*)d_in[12];
  const float* t_b1 = (const float*)d_in[13];
  const float* Wr = (const float*)d_in[14];
  const float* br = (const float*)d_in[15];
  const float* Wt = (const float*)d_in[16];
  const float* bt = (const float*)d_in[17];

  half_t* w16 = (half_t*)d_ws;
  float* cbase = (float*)((char*)d_ws + C_BYTE_OFF);
  float* out = (float*)d_out;

  // zero h / r_out16 / c state every call (deterministic, no cross-call state)
  hipMemsetAsync((char*)d_ws + STATE_BYTE_OFF, 0, STATE_BYTES, stream);

  conv_w<<<(W_TOTAL + 255) / 256, 256, 0, stream>>>(
      rWih0, rWhh0, rWih1, rWhh1, tWih0, tWhh0, tWih1, tWhh1, Wr, Wt, w16);

  for (int k = 0; k < 517; ++k) {
    tick_kernel<<<131, 256, 0, stream>>>(xr, xt, r_b0, r_b1, t_b0, t_b1, br,
                                         bt, w16, cbase, out, k);
  }
}